// Round 1
// baseline (297.755 us; speedup 1.0000x reference)
//
#include <hip/hip_runtime.h>
#include <math.h>

#define N_HEADS 8
#define N_LEVELS 4
#define N_POINTS 4
#define LQ 5440
#define LV 5440
#define BATCH_ 4
#define M_TOT (BATCH_ * LQ)   // 21760

// ---------------- tiled f32 GEMM: C[M,N] = A[M,K] @ W[K,N] + bias[N] ----------------
// BM=64, BN=64, BK=16; 256 threads; each thread 4x4 microtile.
template<int BM, int BN, int BK>
__global__ __launch_bounds__(256) void gemm_bias_f32(
    const float* __restrict__ A, const float* __restrict__ W,
    const float* __restrict__ bias, float* __restrict__ C,
    int M, int N, int K)
{
  __shared__ float As[BK][BM + 4];   // +4 keeps 16B row alignment, breaks bank aliasing
  __shared__ float Ws[BK][BN + 4];
  const int tid = threadIdx.x;
  const int tx = tid & 15;        // -> N
  const int ty = tid >> 4;        // -> M
  const int m0 = blockIdx.y * BM;
  const int n0 = blockIdx.x * BN;

  float acc[4][4] = {};
  for (int k0 = 0; k0 < K; k0 += BK) {
    // A tile 64x16, transposed into As[k][m]
    {
      const int r  = tid >> 2;          // 0..63 row
      const int kk = (tid & 3) * 4;     // 0,4,8,12
      const float4 a = *(const float4*)(A + (size_t)(m0 + r) * K + k0 + kk);
      As[kk+0][r] = a.x; As[kk+1][r] = a.y; As[kk+2][r] = a.z; As[kk+3][r] = a.w;
    }
    // W tile 16x64
    {
      const int kk = tid >> 4;          // 0..15
      const int n  = (tid & 15) * 4;
      *(float4*)&Ws[kk][n] = *(const float4*)(W + (size_t)(k0 + kk) * N + n0 + n);
    }
    __syncthreads();
#pragma unroll
    for (int kk = 0; kk < BK; ++kk) {
      const float4 ra = *(const float4*)&As[kk][ty * 4];
      const float4 rb = *(const float4*)&Ws[kk][tx * 4];
      const float a0[4] = {ra.x, ra.y, ra.z, ra.w};
      const float b0[4] = {rb.x, rb.y, rb.z, rb.w};
#pragma unroll
      for (int i = 0; i < 4; ++i)
#pragma unroll
        for (int j = 0; j < 4; ++j)
          acc[i][j] = fmaf(a0[i], b0[j], acc[i][j]);
    }
    __syncthreads();
  }
  // store with bias, float4
  const float4 bb = *(const float4*)(bias + n0 + tx * 4);
#pragma unroll
  for (int i = 0; i < 4; ++i) {
    const int m = m0 + ty * 4 + i;
    float4 o;
    o.x = acc[i][0] + bb.x; o.y = acc[i][1] + bb.y;
    o.z = acc[i][2] + bb.z; o.w = acc[i][3] + bb.w;
    *(float4*)(C + (size_t)m * N + n0 + tx * 4) = o;
  }
}

// ---------------- fused softmax + bilinear sampling ----------------
// 1 block per (b,q); 256 threads = 8 heads x 32 channels.
__global__ __launch_bounds__(256) void msda_sample_kernel(
    const float* __restrict__ off_buf,    // [M,256]  (h*32 + l*8 + p*2 + xy)
    const float* __restrict__ logit_buf,  // [M,128]  (h*16 + l*4 + p)
    const float* __restrict__ value,      // [B, LV, 256]  (c = h*32 + d)
    const float* __restrict__ ref_pts,    // [B, LQ, 4, 2]
    const int*  __restrict__ sshapes,     // [4,2] (H,W)
    const int*  __restrict__ lstart,      // [4]
    float* __restrict__ samp)             // [M, 256]
{
  __shared__ float off_s[256];
  __shared__ float logit_s[128];
  __shared__ float ref_s[8];
  __shared__ int   shp_s[8];
  __shared__ int   st_s[4];
  const int tid = threadIdx.x;
  const int qg = blockIdx.x;             // 0..M-1
  const int b = qg / LQ;

  off_s[tid] = off_buf[(size_t)qg * 256 + tid];
  if (tid < 128) logit_s[tid] = logit_buf[(size_t)qg * 128 + tid];
  if (tid < 8)   ref_s[tid]   = ref_pts[(size_t)qg * 8 + tid];
  if (tid >= 32 && tid < 40) shp_s[tid - 32] = sshapes[tid - 32];
  if (tid >= 64 && tid < 68) st_s[tid - 64] = lstart[tid - 64];
  __syncthreads();

  const int h = tid >> 5, d = tid & 31;

  // softmax over this head's 16 logits (redundant across the 32 lanes of a head; cheap)
  float mx = -1e30f;
#pragma unroll
  for (int i = 0; i < 16; ++i) mx = fmaxf(mx, logit_s[h * 16 + i]);
  float ssum = 0.f;
#pragma unroll
  for (int i = 0; i < 16; ++i) ssum += __expf(logit_s[h * 16 + i] - mx);
  const float inv = 1.f / ssum;

  float acc = 0.f;
#pragma unroll
  for (int l = 0; l < 4; ++l) {
    const int Hl = shp_s[2 * l], Wl = shp_s[2 * l + 1];
    const int s0 = st_s[l];
    const float fx = ref_s[2 * l + 0] * (float)Wl - 0.5f;
    const float fy = ref_s[2 * l + 1] * (float)Hl - 0.5f;
    const float* vbase = value + ((size_t)b * LV + s0) * 256 + h * 32 + d;
#pragma unroll
    for (int p = 0; p < 4; ++p) {
      const float x = fx + off_s[h * 32 + l * 8 + p * 2 + 0];
      const float y = fy + off_s[h * 32 + l * 8 + p * 2 + 1];
      const float xf = floorf(x), yf = floorf(y);
      const float wx1 = x - xf, wy1 = y - yf;
      const int x0 = (int)xf, y0 = (int)yf;
      const float aw = __expf(logit_s[h * 16 + l * 4 + p] - mx) * inv;
      float sacc = 0.f;
#pragma unroll
      for (int dy = 0; dy < 2; ++dy) {
#pragma unroll
        for (int dx = 0; dx < 2; ++dx) {
          const int xi = x0 + dx, yi = y0 + dy;
          const float vld = ((xi >= 0) & (xi < Wl) & (yi >= 0) & (yi < Hl)) ? 1.f : 0.f;
          const int xc = min(max(xi, 0), Wl - 1);
          const int yc = min(max(yi, 0), Hl - 1);
          const float g = vbase[(size_t)(yc * Wl + xc) * 256];
          const float cw = (dx ? wx1 : 1.f - wx1) * (dy ? wy1 : 1.f - wy1);
          sacc = fmaf(cw * vld, g, sacc);
        }
      }
      acc = fmaf(aw, sacc, acc);
    }
  }
  samp[(size_t)qg * 256 + tid] = acc;
}

extern "C" void kernel_launch(void* const* d_in, const int* in_sizes, int n_in,
                              void* d_out, int out_size, void* d_ws, size_t ws_size,
                              hipStream_t stream) {
  const float* query         = (const float*)d_in[0];
  const float* ref_pts       = (const float*)d_in[1];
  const float* input_flatten = (const float*)d_in[2];
  const int*   sshapes       = (const int*)d_in[3];
  const int*   lstart        = (const int*)d_in[4];
  const float* w_val  = (const float*)d_in[5];
  const float* b_val  = (const float*)d_in[6];
  const float* w_off  = (const float*)d_in[7];
  const float* b_off  = (const float*)d_in[8];
  const float* w_attn = (const float*)d_in[9];
  const float* b_attn = (const float*)d_in[10];
  const float* w_out  = (const float*)d_in[11];
  const float* b_out  = (const float*)d_in[12];
  float* out = (float*)d_out;

  float* value_buf = (float*)d_ws;                          // M*256
  float* off_buf   = value_buf + (size_t)M_TOT * 256;       // M*256
  float* logit_buf = off_buf   + (size_t)M_TOT * 256;       // M*128
  float* samp_buf  = logit_buf + (size_t)M_TOT * 128;       // M*256
  // total: 21760 * 896 * 4B = 78.0 MB

  dim3 blk(256);
  gemm_bias_f32<64, 64, 16><<<dim3(4, M_TOT / 64), blk, 0, stream>>>(
      input_flatten, w_val, b_val, value_buf, M_TOT, 256, 256);
  gemm_bias_f32<64, 64, 16><<<dim3(4, M_TOT / 64), blk, 0, stream>>>(
      query, w_off, b_off, off_buf, M_TOT, 256, 256);
  gemm_bias_f32<64, 64, 16><<<dim3(2, M_TOT / 64), blk, 0, stream>>>(
      query, w_attn, b_attn, logit_buf, M_TOT, 128, 256);
  msda_sample_kernel<<<dim3(M_TOT), blk, 0, stream>>>(
      off_buf, logit_buf, value_buf, ref_pts, sshapes, lstart, samp_buf);
  gemm_bias_f32<64, 64, 16><<<dim3(4, M_TOT / 64), blk, 0, stream>>>(
      samp_buf, w_out, b_out, out, M_TOT, 256, 256);
}

// Round 2
// 253.423 us; speedup vs baseline: 1.1749x; 1.1749x over previous
//
#include <hip/hip_runtime.h>
#include <math.h>

#define N_HEADS 8
#define N_LEVELS 4
#define N_POINTS 4
#define LQ 5440
#define LV 5440
#define BATCH_ 4
#define M_TOT (BATCH_ * LQ)   // 21760

// ---------------- 64x64 tiled f32 GEMM (kept for N=128 logit GEMM) ----------------
template<int BM, int BN, int BK>
__global__ __launch_bounds__(256) void gemm_bias_f32(
    const float* __restrict__ A, const float* __restrict__ W,
    const float* __restrict__ bias, float* __restrict__ C,
    int M, int N, int K)
{
  __shared__ float As[BK][BM + 4];
  __shared__ float Ws[BK][BN + 4];
  const int tid = threadIdx.x;
  const int tx = tid & 15;
  const int ty = tid >> 4;
  const int m0 = blockIdx.y * BM;
  const int n0 = blockIdx.x * BN;

  float acc[4][4] = {};
  for (int k0 = 0; k0 < K; k0 += BK) {
    {
      const int r  = tid >> 2;
      const int kk = (tid & 3) * 4;
      const float4 a = *(const float4*)(A + (size_t)(m0 + r) * K + k0 + kk);
      As[kk+0][r] = a.x; As[kk+1][r] = a.y; As[kk+2][r] = a.z; As[kk+3][r] = a.w;
    }
    {
      const int kk = tid >> 4;
      const int n  = (tid & 15) * 4;
      *(float4*)&Ws[kk][n] = *(const float4*)(W + (size_t)(k0 + kk) * N + n0 + n);
    }
    __syncthreads();
#pragma unroll
    for (int kk = 0; kk < BK; ++kk) {
      const float4 ra = *(const float4*)&As[kk][ty * 4];
      const float4 rb = *(const float4*)&Ws[kk][tx * 4];
      const float a0[4] = {ra.x, ra.y, ra.z, ra.w};
      const float b0[4] = {rb.x, rb.y, rb.z, rb.w};
#pragma unroll
      for (int i = 0; i < 4; ++i)
#pragma unroll
        for (int j = 0; j < 4; ++j)
          acc[i][j] = fmaf(a0[i], b0[j], acc[i][j]);
    }
    __syncthreads();
  }
  const float4 bb = *(const float4*)(bias + n0 + tx * 4);
#pragma unroll
  for (int i = 0; i < 4; ++i) {
    const int m = m0 + ty * 4 + i;
    float4 o;
    o.x = acc[i][0] + bb.x; o.y = acc[i][1] + bb.y;
    o.z = acc[i][2] + bb.z; o.w = acc[i][3] + bb.w;
    *(float4*)(C + (size_t)m * N + n0 + tx * 4) = o;
  }
}

// ---------------- 128x128 tiled f32 GEMM, 8x8 microtile (2x2 of float4) ----------------
__global__ __launch_bounds__(256) void gemm128_bias_f32(
    const float* __restrict__ A, const float* __restrict__ W,
    const float* __restrict__ bias, float* __restrict__ C,
    int M, int N, int K)
{
  __shared__ float As[16][128 + 4];
  __shared__ float Ws[16][128 + 4];
  const int tid = threadIdx.x;
  const int tx = tid & 15;        // -> N quad
  const int ty = tid >> 4;        // -> M quad
  const int m0 = blockIdx.y * 128;
  const int n0 = blockIdx.x * 128;

  float acc[2][2][4][4] = {};

  for (int k0 = 0; k0 < K; k0 += 16) {
    // A tile 128x16 -> transposed As[k][m]
#pragma unroll
    for (int it = 0; it < 2; ++it) {
      const int idx = tid + it * 256;
      const int r  = idx >> 2;
      const int kc = (idx & 3) * 4;
      const float4 a = *(const float4*)(A + (size_t)(m0 + r) * K + k0 + kc);
      As[kc+0][r] = a.x; As[kc+1][r] = a.y; As[kc+2][r] = a.z; As[kc+3][r] = a.w;
    }
    // W tile 16x128
#pragma unroll
    for (int it = 0; it < 2; ++it) {
      const int idx = tid + it * 256;
      const int kk = idx >> 5;
      const int nc = (idx & 31) * 4;
      *(float4*)&Ws[kk][nc] = *(const float4*)(W + (size_t)(k0 + kk) * N + n0 + nc);
    }
    __syncthreads();
#pragma unroll
    for (int kk = 0; kk < 16; ++kk) {
      const float4 a0 = *(const float4*)&As[kk][ty * 4];
      const float4 a1 = *(const float4*)&As[kk][64 + ty * 4];
      const float4 b0 = *(const float4*)&Ws[kk][tx * 4];
      const float4 b1 = *(const float4*)&Ws[kk][64 + tx * 4];
      const float av[2][4] = {{a0.x, a0.y, a0.z, a0.w}, {a1.x, a1.y, a1.z, a1.w}};
      const float bv[2][4] = {{b0.x, b0.y, b0.z, b0.w}, {b1.x, b1.y, b1.z, b1.w}};
#pragma unroll
      for (int bi = 0; bi < 2; ++bi)
#pragma unroll
        for (int bj = 0; bj < 2; ++bj)
#pragma unroll
          for (int i = 0; i < 4; ++i)
#pragma unroll
            for (int j = 0; j < 4; ++j)
              acc[bi][bj][i][j] = fmaf(av[bi][i], bv[bj][j], acc[bi][bj][i][j]);
    }
    __syncthreads();
  }
  const float4 bb0 = *(const float4*)(bias + n0 + tx * 4);
  const float4 bb1 = *(const float4*)(bias + n0 + 64 + tx * 4);
  const float bbv[2][4] = {{bb0.x, bb0.y, bb0.z, bb0.w}, {bb1.x, bb1.y, bb1.z, bb1.w}};
#pragma unroll
  for (int bi = 0; bi < 2; ++bi) {
#pragma unroll
    for (int i = 0; i < 4; ++i) {
      const int m = m0 + bi * 64 + ty * 4 + i;
#pragma unroll
      for (int bj = 0; bj < 2; ++bj) {
        float4 o;
        o.x = acc[bi][bj][i][0] + bbv[bj][0];
        o.y = acc[bi][bj][i][1] + bbv[bj][1];
        o.z = acc[bi][bj][i][2] + bbv[bj][2];
        o.w = acc[bi][bj][i][3] + bbv[bj][3];
        *(float4*)(C + (size_t)m * N + n0 + bj * 64 + tx * 4) = o;
      }
    }
  }
}

// ---------------- fused softmax + bilinear sampling, v2 ----------------
// 256 threads = 4 queries x (8 heads x 8 channel-groups of 4). float4 gathers.
__global__ __launch_bounds__(256) void msda_sample_v2(
    const float* __restrict__ off_buf,    // [M,256]  (h*32 + l*8 + p*2 + xy)
    const float* __restrict__ logit_buf,  // [M,128]  (h*16 + l*4 + p)
    const float* __restrict__ value,      // [B, LV, 256]
    const float* __restrict__ ref_pts,    // [B, LQ, 4, 2]
    const int*  __restrict__ sshapes,     // [4,2] (H,W)
    const int*  __restrict__ lstart,      // [4]
    float* __restrict__ samp)             // [M, 256]
{
  __shared__ float off_s[4][256];
  __shared__ float logit_s[4][128];
  __shared__ float ref_s[4][8];
  __shared__ int   shp_s[8];
  __shared__ int   st_s[4];
  const int tid = threadIdx.x;
  const int q0 = blockIdx.x * 4;

  {
    const int q = tid >> 6, j = (tid & 63) * 4;
    *(float4*)&off_s[q][j] = *(const float4*)(off_buf + (size_t)(q0 + q) * 256 + j);
  }
  if (tid < 128) {
    const int q = tid >> 5, j = (tid & 31) * 4;
    *(float4*)&logit_s[q][j] = *(const float4*)(logit_buf + (size_t)(q0 + q) * 128 + j);
  }
  if (tid < 32) {
    const int q = tid >> 3, j = tid & 7;
    ref_s[q][j] = ref_pts[(size_t)(q0 + q) * 8 + j];
  }
  if (tid >= 64 && tid < 72) shp_s[tid - 64] = sshapes[tid - 64];
  if (tid >= 96 && tid < 100) st_s[tid - 96] = lstart[tid - 96];
  __syncthreads();

  const int q  = tid >> 6;
  const int l6 = tid & 63;
  const int h  = l6 >> 3;
  const int dg = l6 & 7;
  const int qg = q0 + q;
  const int b  = blockIdx.x / (LQ / 4);

  // softmax over this head's 16 logits (8x redundant across dg lanes; cheap)
  float ex[16];
  float mx = -1e30f;
#pragma unroll
  for (int i = 0; i < 16; ++i) mx = fmaxf(mx, logit_s[q][h * 16 + i]);
  float ssum = 0.f;
#pragma unroll
  for (int i = 0; i < 16; ++i) { ex[i] = __expf(logit_s[q][h * 16 + i] - mx); ssum += ex[i]; }
  const float inv = 1.f / ssum;

  float4 acc = {0.f, 0.f, 0.f, 0.f};
  const float* vrow = value + (size_t)b * LV * 256 + h * 32 + dg * 4;

#pragma unroll
  for (int l = 0; l < 4; ++l) {
    const int Hl = shp_s[2 * l], Wl = shp_s[2 * l + 1];
    const float fx = ref_s[q][2 * l + 0] * (float)Wl - 0.5f;
    const float fy = ref_s[q][2 * l + 1] * (float)Hl - 0.5f;
    const float* vbase = vrow + (size_t)st_s[l] * 256;
#pragma unroll
    for (int p = 0; p < 4; ++p) {
      const float x = fx + off_s[q][h * 32 + l * 8 + p * 2 + 0];
      const float y = fy + off_s[q][h * 32 + l * 8 + p * 2 + 1];
      const float xf = floorf(x), yf = floorf(y);
      const float wx1 = x - xf, wy1 = y - yf;
      const int x0i = (int)xf, y0i = (int)yf;
      const float aw = ex[l * 4 + p] * inv;

      const float vx0 = (x0i >= 0 && x0i < Wl) ? 1.f : 0.f;
      const float vx1 = (x0i + 1 >= 0 && x0i + 1 < Wl) ? 1.f : 0.f;
      const float vy0 = (y0i >= 0 && y0i < Hl) ? 1.f : 0.f;
      const float vy1 = (y0i + 1 >= 0 && y0i + 1 < Hl) ? 1.f : 0.f;
      const int xc0 = min(max(x0i, 0), Wl - 1);
      const int xc1 = min(max(x0i + 1, 0), Wl - 1);
      const int yc0 = min(max(y0i, 0), Hl - 1);
      const int yc1 = min(max(y0i + 1, 0), Hl - 1);
      const float wx0 = 1.f - wx1, wy0 = 1.f - wy1;

      const float w00 = aw * wy0 * wx0 * vy0 * vx0;
      const float w01 = aw * wy0 * wx1 * vy0 * vx1;
      const float w10 = aw * wy1 * wx0 * vy1 * vx0;
      const float w11 = aw * wy1 * wx1 * vy1 * vx1;

      const float4 g00 = *(const float4*)(vbase + (size_t)(yc0 * Wl + xc0) * 256);
      const float4 g01 = *(const float4*)(vbase + (size_t)(yc0 * Wl + xc1) * 256);
      const float4 g10 = *(const float4*)(vbase + (size_t)(yc1 * Wl + xc0) * 256);
      const float4 g11 = *(const float4*)(vbase + (size_t)(yc1 * Wl + xc1) * 256);

      acc.x = fmaf(w00, g00.x, acc.x); acc.y = fmaf(w00, g00.y, acc.y);
      acc.z = fmaf(w00, g00.z, acc.z); acc.w = fmaf(w00, g00.w, acc.w);
      acc.x = fmaf(w01, g01.x, acc.x); acc.y = fmaf(w01, g01.y, acc.y);
      acc.z = fmaf(w01, g01.z, acc.z); acc.w = fmaf(w01, g01.w, acc.w);
      acc.x = fmaf(w10, g10.x, acc.x); acc.y = fmaf(w10, g10.y, acc.y);
      acc.z = fmaf(w10, g10.z, acc.z); acc.w = fmaf(w10, g10.w, acc.w);
      acc.x = fmaf(w11, g11.x, acc.x); acc.y = fmaf(w11, g11.y, acc.y);
      acc.z = fmaf(w11, g11.z, acc.z); acc.w = fmaf(w11, g11.w, acc.w);
    }
  }
  *(float4*)(samp + (size_t)qg * 256 + l6 * 4) = acc;
}

extern "C" void kernel_launch(void* const* d_in, const int* in_sizes, int n_in,
                              void* d_out, int out_size, void* d_ws, size_t ws_size,
                              hipStream_t stream) {
  const float* query         = (const float*)d_in[0];
  const float* ref_pts       = (const float*)d_in[1];
  const float* input_flatten = (const float*)d_in[2];
  const int*   sshapes       = (const int*)d_in[3];
  const int*   lstart        = (const int*)d_in[4];
  const float* w_val  = (const float*)d_in[5];
  const float* b_val  = (const float*)d_in[6];
  const float* w_off  = (const float*)d_in[7];
  const float* b_off  = (const float*)d_in[8];
  const float* w_attn = (const float*)d_in[9];
  const float* b_attn = (const float*)d_in[10];
  const float* w_out  = (const float*)d_in[11];
  const float* b_out  = (const float*)d_in[12];
  float* out = (float*)d_out;

  float* value_buf = (float*)d_ws;                          // M*256
  float* off_buf   = value_buf + (size_t)M_TOT * 256;       // M*256
  float* logit_buf = off_buf   + (size_t)M_TOT * 256;       // M*128
  float* samp_buf  = logit_buf + (size_t)M_TOT * 128;       // M*256
  // total: 21760 * 896 * 4B = 78.0 MB

  dim3 blk(256);
  gemm128_bias_f32<<<dim3(2, M_TOT / 128), blk, 0, stream>>>(
      input_flatten, w_val, b_val, value_buf, M_TOT, 256, 256);
  gemm128_bias_f32<<<dim3(2, M_TOT / 128), blk, 0, stream>>>(
      query, w_off, b_off, off_buf, M_TOT, 256, 256);
  gemm_bias_f32<64, 64, 16><<<dim3(2, M_TOT / 64), blk, 0, stream>>>(
      query, w_attn, b_attn, logit_buf, M_TOT, 128, 256);
  msda_sample_v2<<<dim3(M_TOT / 4), blk, 0, stream>>>(
      off_buf, logit_buf, value_buf, ref_pts, sshapes, lstart, samp_buf);
  gemm128_bias_f32<<<dim3(2, M_TOT / 128), blk, 0, stream>>>(
      samp_buf, w_out, b_out, out, M_TOT, 256, 256);
}

// Round 3
// 132.689 us; speedup vs baseline: 2.2440x; 1.9099x over previous
//
#include <hip/hip_runtime.h>
#include <math.h>

#define N_HEADS 8
#define N_LEVELS 4
#define N_POINTS 4
#define LQ 5440
#define LV 5440
#define BATCH_ 4
#define M_TOT (BATCH_ * LQ)   // 21760

typedef __bf16 bf16x8 __attribute__((ext_vector_type(8)));
typedef float f32x4 __attribute__((ext_vector_type(4)));
typedef unsigned int uint_t;

__device__ __forceinline__ unsigned short rne_bf16(float x) {
  uint_t u = __float_as_uint(x);
  uint_t r = u + 0x7fffu + ((u >> 16) & 1u);
  return (unsigned short)(r >> 16);
}
__device__ __forceinline__ float bf16_to_f(unsigned short h) {
  return __uint_as_float(((uint_t)h) << 16);
}

// ---------------- input conversion: query -> Q3 (hi|lo), input_flatten -> IFh ----------------
__global__ __launch_bounds__(256) void conv_inputs(
    const float* __restrict__ q, const float* __restrict__ iff,
    unsigned short* __restrict__ Q3, unsigned short* __restrict__ IFh)
{
  const int t = blockIdx.x * 256 + threadIdx.x;   // 0 .. M*64
  const int r = t >> 6;
  const int c = (t & 63) * 4;
  const float4 qa = *(const float4*)(q + (size_t)r * 256 + c);
  ushort4 h, l;
  {
    const float v[4] = {qa.x, qa.y, qa.z, qa.w};
    unsigned short hh[4], ll[4];
#pragma unroll
    for (int i = 0; i < 4; ++i) {
      hh[i] = rne_bf16(v[i]);
      ll[i] = rne_bf16(v[i] - bf16_to_f(hh[i]));
    }
    h = make_ushort4(hh[0], hh[1], hh[2], hh[3]);
    l = make_ushort4(ll[0], ll[1], ll[2], ll[3]);
  }
  *(ushort4*)(Q3 + (size_t)r * 512 + c) = h;
  *(ushort4*)(Q3 + (size_t)r * 512 + 256 + c) = l;
  const float4 fa = *(const float4*)(iff + (size_t)r * 256 + c);
  *(ushort4*)(IFh + (size_t)r * 256 + c) =
      make_ushort4(rne_bf16(fa.x), rne_bf16(fa.y), rne_bf16(fa.z), rne_bf16(fa.w));
}

// ---------------- weight conversion (transpose + bf16 split) ----------------
// x3 layout Wt3[n][0..255]=hi, [256..511]=hi, [512..767]=lo   (pairs with A=[hi|lo|hi-wrap])
// hi layout Wt[n][0..255]=hi
__global__ __launch_bounds__(256) void conv_weights(
    const float* __restrict__ w_off, const float* __restrict__ w_out,
    const float* __restrict__ w_val, const float* __restrict__ w_attn,
    unsigned short* __restrict__ Woff3, unsigned short* __restrict__ Wo3,
    unsigned short* __restrict__ Wvt, unsigned short* __restrict__ Wat)
{
  __shared__ float tbuf[64][65];
  const int tid = threadIdx.x;
  const int k0 = blockIdx.x * 64;
  const int yy = blockIdx.y;
  const float* src; unsigned short* dst; int N; int mode; int ntile;
  if (yy < 4)       { src = w_off;  dst = Woff3; N = 256; mode = 1; ntile = yy; }
  else if (yy < 8)  { src = w_out;  dst = Wo3;   N = 256; mode = 1; ntile = yy - 4; }
  else if (yy < 12) { src = w_val;  dst = Wvt;   N = 256; mode = 0; ntile = yy - 8; }
  else              { src = w_attn; dst = Wat;   N = 128; mode = 0; ntile = yy - 12; }
  const int n0 = ntile * 64;
#pragma unroll
  for (int i = 0; i < 16; ++i) {
    const int r = (tid >> 6) + i * 4;
    const int c = tid & 63;
    tbuf[r][c] = src[(size_t)(k0 + r) * N + n0 + c];
  }
  __syncthreads();
#pragma unroll
  for (int i = 0; i < 16; ++i) {
    const int n = (tid >> 6) + i * 4;
    const int kk = tid & 63;
    const float v = tbuf[kk][n];
    const unsigned short h = rne_bf16(v);
    if (mode) {
      const unsigned short l = rne_bf16(v - bf16_to_f(h));
      const size_t rowb = (size_t)(n0 + n) * 768;
      dst[rowb + k0 + kk] = h;
      dst[rowb + 256 + k0 + kk] = h;
      dst[rowb + 512 + k0 + kk] = l;
    } else {
      dst[(size_t)(n0 + n) * 256 + k0 + kk] = h;
    }
  }
}

// ---------------- bf16 MFMA GEMM, m97 structure ----------------
// C[M,N] = A[M,K] @ Bt[N,K]^T + bias. 128x128 tile, BK=64, 4 waves (2x2 of 64x64).
// LDS staged via global_load_lds(16B) with inverse-swizzled source; ds_read_b128 XOR-swizzled.
template<int KSTEPS, int AMOD, bool OUT_BF16>
__global__ __launch_bounds__(256) void gemm_mfma(
    const unsigned short* __restrict__ A, int lda,
    const unsigned short* __restrict__ Bt,   // [N][KSTEPS*64]
    const float* __restrict__ bias,
    void* __restrict__ Cout, int ldc)
{
  constexpr int LDB = KSTEPS * 64;
  __shared__ unsigned short As[128 * 64];
  __shared__ unsigned short Bs[128 * 64];
  const int tid = threadIdx.x;
  const int w = tid >> 6, lane = tid & 63;
  const int wm = w >> 1, wn = w & 1;
  const int lr = lane & 15, lk = lane >> 4;
  const int m0 = blockIdx.y * 128, n0 = blockIdx.x * 128;

  f32x4 acc[4][4] = {};

  for (int t = 0; t < KSTEPS; ++t) {
    int ka = t * 64; if (ka >= AMOD) ka -= AMOD;
    const int kb = t * 64;
    // stage A tile [128][64] bf16 (16KB): 4 calls x 4 waves x 64 lanes x 16B
#pragma unroll
    for (int i = 0; i < 4; ++i) {
      const int rbase = i * 32 + w * 8;
      const int row = rbase + (lane >> 3);
      const int slot = lane & 7;
      const int gs = slot ^ (row & 7);                 // inverse-swizzle the SOURCE (rule 21)
      const unsigned short* gp = A + (size_t)(m0 + row) * lda + ka + gs * 8;
      __builtin_amdgcn_global_load_lds(
          (const __attribute__((address_space(1))) uint_t*)gp,
          (__attribute__((address_space(3))) uint_t*)(As + rbase * 64), 16, 0, 0);
    }
#pragma unroll
    for (int i = 0; i < 4; ++i) {
      const int rbase = i * 32 + w * 8;
      const int row = rbase + (lane >> 3);
      const int slot = lane & 7;
      const int gs = slot ^ (row & 7);
      const unsigned short* gp = Bt + (size_t)(n0 + row) * LDB + kb + gs * 8;
      __builtin_amdgcn_global_load_lds(
          (const __attribute__((address_space(1))) uint_t*)gp,
          (__attribute__((address_space(3))) uint_t*)(Bs + rbase * 64), 16, 0, 0);
    }
    asm volatile("s_waitcnt vmcnt(0)" ::: "memory");
    __syncthreads();
#pragma unroll
    for (int kk = 0; kk < 2; ++kk) {
      bf16x8 af[4], bfv[4];
#pragma unroll
      for (int m = 0; m < 4; ++m) {
        const int row = wm * 64 + m * 16 + lr;
        const int so = (kk * 4 + lk) ^ (row & 7);      // swizzled read
        af[m] = *(const bf16x8*)((const char*)As + row * 128 + so * 16);
      }
#pragma unroll
      for (int n = 0; n < 4; ++n) {
        const int row = wn * 64 + n * 16 + lr;
        const int so = (kk * 4 + lk) ^ (row & 7);
        bfv[n] = *(const bf16x8*)((const char*)Bs + row * 128 + so * 16);
      }
#pragma unroll
      for (int m = 0; m < 4; ++m)
#pragma unroll
        for (int n = 0; n < 4; ++n)
          acc[m][n] = __builtin_amdgcn_mfma_f32_16x16x32_bf16(af[m], bfv[n], acc[m][n], 0, 0, 0);
    }
    __syncthreads();
  }
  // epilogue: C/D layout col=lane&15, row=(lane>>4)*4+reg
#pragma unroll
  for (int n = 0; n < 4; ++n) {
    const int col = n0 + wn * 64 + n * 16 + lr;
    const float bv = bias[col];
#pragma unroll
    for (int m = 0; m < 4; ++m) {
      const int rbase = m0 + wm * 64 + m * 16 + lk * 4;
#pragma unroll
      for (int j = 0; j < 4; ++j) {
        const float v = acc[m][n][j] + bv;
        if (OUT_BF16) ((unsigned short*)Cout)[(size_t)(rbase + j) * ldc + col] = rne_bf16(v);
        else          ((float*)Cout)[(size_t)(rbase + j) * ldc + col] = v;
      }
    }
  }
}

// ---------------- fused softmax + bilinear sampling, v3 (bf16 value, 8ch/thread) ----------------
// block 256 = 8 queries x (8 heads x 4 groups-of-8ch). Writes samp3 [M][512] = (hi|lo).
__global__ __launch_bounds__(256) void msda_sample_v3(
    const float* __restrict__ off_buf,            // [M,256]
    const unsigned short* __restrict__ logit_buf, // [M,128] bf16
    const unsigned short* __restrict__ value,     // [B,LV,256] bf16
    const float* __restrict__ ref_pts,            // [B,LQ,4,2]
    const int*  __restrict__ sshapes, const int* __restrict__ lstart,
    unsigned short* __restrict__ samp3)           // [M,512]
{
  __shared__ float off_s[8][256];
  __shared__ float logit_s[8][128];
  __shared__ float ref_s[8][8];
  __shared__ int   shp_s[8];
  __shared__ int   st_s[4];
  const int tid = threadIdx.x;
  const int q0 = blockIdx.x * 8;

#pragma unroll
  for (int i = 0; i < 2; ++i) {
    const int j = tid + i * 256;          // 512 float4 chunks
    const int qq = j >> 6, cc = (j & 63) * 4;
    *(float4*)&off_s[qq][cc] = *(const float4*)(off_buf + (size_t)(q0 + qq) * 256 + cc);
  }
  if (tid < 128) {
    const int qq = tid >> 4, cc = (tid & 15) * 8;
    const uint4 g = *(const uint4*)(logit_buf + (size_t)(q0 + qq) * 128 + cc);
    const uint_t u[4] = {g.x, g.y, g.z, g.w};
#pragma unroll
    for (int k = 0; k < 4; ++k) {
      logit_s[qq][cc + 2 * k]     = __uint_as_float(u[k] << 16);
      logit_s[qq][cc + 2 * k + 1] = __uint_as_float(u[k] & 0xffff0000u);
    }
  }
  if (tid < 64) ref_s[tid >> 3][tid & 7] = ref_pts[(size_t)(q0 + (tid >> 3)) * 8 + (tid & 7)];
  if (tid >= 64 && tid < 72) shp_s[tid - 64] = sshapes[tid - 64];
  if (tid >= 96 && tid < 100) st_s[tid - 96] = lstart[tid - 96];
  __syncthreads();

  const int q  = tid >> 5;
  const int l5 = tid & 31;
  const int h  = l5 >> 2;
  const int dg = l5 & 3;
  const int qg = q0 + q;
  const int b  = blockIdx.x / (LQ / 8);   // 680 blocks per batch

  float ex[16];
  float mx = -1e30f;
#pragma unroll
  for (int i = 0; i < 16; ++i) mx = fmaxf(mx, logit_s[q][h * 16 + i]);
  float ssum = 0.f;
#pragma unroll
  for (int i = 0; i < 16; ++i) { ex[i] = __expf(logit_s[q][h * 16 + i] - mx); ssum += ex[i]; }
  const float inv = 1.f / ssum;

  const int chbase = h * 32 + dg * 8;
  const unsigned short* vrow = value + (size_t)b * LV * 256 + chbase;
  float acc[8] = {};

#pragma unroll
  for (int l = 0; l < 4; ++l) {
    const int Hl = shp_s[2 * l], Wl = shp_s[2 * l + 1];
    const float fx = ref_s[q][2 * l + 0] * (float)Wl - 0.5f;
    const float fy = ref_s[q][2 * l + 1] * (float)Hl - 0.5f;
    const unsigned short* vb = vrow + (size_t)st_s[l] * 256;
#pragma unroll
    for (int p = 0; p < 4; ++p) {
      const float x = fx + off_s[q][h * 32 + l * 8 + p * 2 + 0];
      const float y = fy + off_s[q][h * 32 + l * 8 + p * 2 + 1];
      const float xf = floorf(x), yf = floorf(y);
      const float wx1 = x - xf, wy1 = y - yf;
      const int x0i = (int)xf, y0i = (int)yf;
      const float aw = ex[l * 4 + p] * inv;

      const float vx0 = (x0i >= 0 && x0i < Wl) ? 1.f : 0.f;
      const float vx1 = (x0i + 1 >= 0 && x0i + 1 < Wl) ? 1.f : 0.f;
      const float vy0 = (y0i >= 0 && y0i < Hl) ? 1.f : 0.f;
      const float vy1 = (y0i + 1 >= 0 && y0i + 1 < Hl) ? 1.f : 0.f;
      const int xc0 = min(max(x0i, 0), Wl - 1);
      const int xc1 = min(max(x0i + 1, 0), Wl - 1);
      const int yc0 = min(max(y0i, 0), Hl - 1);
      const int yc1 = min(max(y0i + 1, 0), Hl - 1);
      const float wx0 = 1.f - wx1, wy0 = 1.f - wy1;

      const float w00 = aw * wy0 * wx0 * vy0 * vx0;
      const float w01 = aw * wy0 * wx1 * vy0 * vx1;
      const float w10 = aw * wy1 * wx0 * vy1 * vx0;
      const float w11 = aw * wy1 * wx1 * vy1 * vx1;

      const uint4 g00 = *(const uint4*)(vb + (size_t)(yc0 * Wl + xc0) * 256);
      const uint4 g01 = *(const uint4*)(vb + (size_t)(yc0 * Wl + xc1) * 256);
      const uint4 g10 = *(const uint4*)(vb + (size_t)(yc1 * Wl + xc0) * 256);
      const uint4 g11 = *(const uint4*)(vb + (size_t)(yc1 * Wl + xc1) * 256);

      const uint4 gs[4] = {g00, g01, g10, g11};
      const float ws[4] = {w00, w01, w10, w11};
#pragma unroll
      for (int c = 0; c < 4; ++c) {
        const uint_t u[4] = {gs[c].x, gs[c].y, gs[c].z, gs[c].w};
        const float wv = ws[c];
#pragma unroll
        for (int k = 0; k < 4; ++k) {
          acc[2 * k]     = fmaf(wv, __uint_as_float(u[k] << 16), acc[2 * k]);
          acc[2 * k + 1] = fmaf(wv, __uint_as_float(u[k] & 0xffff0000u), acc[2 * k + 1]);
        }
      }
    }
  }
  unsigned short h8[8], l8[8];
#pragma unroll
  for (int i = 0; i < 8; ++i) {
    h8[i] = rne_bf16(acc[i]);
    l8[i] = rne_bf16(acc[i] - bf16_to_f(h8[i]));
  }
  unsigned short* op = samp3 + (size_t)qg * 512 + chbase;
  *(ushort4*)(op)       = make_ushort4(h8[0], h8[1], h8[2], h8[3]);
  *(ushort4*)(op + 4)   = make_ushort4(h8[4], h8[5], h8[6], h8[7]);
  *(ushort4*)(op + 256) = make_ushort4(l8[0], l8[1], l8[2], l8[3]);
  *(ushort4*)(op + 260) = make_ushort4(l8[4], l8[5], l8[6], l8[7]);
}

extern "C" void kernel_launch(void* const* d_in, const int* in_sizes, int n_in,
                              void* d_out, int out_size, void* d_ws, size_t ws_size,
                              hipStream_t stream) {
  const float* query         = (const float*)d_in[0];
  const float* ref_pts       = (const float*)d_in[1];
  const float* input_flatten = (const float*)d_in[2];
  const int*   sshapes       = (const int*)d_in[3];
  const int*   lstart        = (const int*)d_in[4];
  const float* w_val  = (const float*)d_in[5];
  const float* b_val  = (const float*)d_in[6];
  const float* w_off  = (const float*)d_in[7];
  const float* b_off  = (const float*)d_in[8];
  const float* w_attn = (const float*)d_in[9];
  const float* b_attn = (const float*)d_in[10];
  const float* w_out  = (const float*)d_in[11];
  const float* b_out  = (const float*)d_in[12];
  float* out = (float*)d_out;

  char* ws = (char*)d_ws;
  unsigned short* Q3     = (unsigned short*)(ws);                 // 22,282,240 B  (later reused as samp3)
  unsigned short* IFh    = (unsigned short*)(ws + 22282240);      // 11,141,120
  unsigned short* valb   = (unsigned short*)(ws + 33423360);      // 11,141,120
  float*          offb   = (float*)(ws + 44564480);               // 22,282,240
  unsigned short* logitb = (unsigned short*)(ws + 66846720);      //  5,570,560
  unsigned short* Woff3  = (unsigned short*)(ws + 72417280);      //    393,216
  unsigned short* Wo3    = (unsigned short*)(ws + 72810496);      //    393,216
  unsigned short* Wvt    = (unsigned short*)(ws + 73203712);      //    131,072
  unsigned short* Wat    = (unsigned short*)(ws + 73334784);      //     65,536
  unsigned short* samp3  = Q3;  // Q3 dead after the off/logit GEMMs; sampler runs after them

  dim3 blk(256);
  conv_inputs<<<dim3(M_TOT / 4), blk, 0, stream>>>(query, input_flatten, Q3, IFh);
  conv_weights<<<dim3(4, 14), blk, 0, stream>>>(w_off, w_out, w_val, w_attn, Woff3, Wo3, Wvt, Wat);
  // value = IFh @ w_val (plain bf16), out bf16
  gemm_mfma<4, (1 << 20), true><<<dim3(2, M_TOT / 128), blk, 0, stream>>>(
      IFh, 256, Wvt, b_val, (void*)valb, 256);
  // off = Q (hi|lo|hi-wrap) @ w_off x3, out f32
  gemm_mfma<12, 512, false><<<dim3(2, M_TOT / 128), blk, 0, stream>>>(
      Q3, 512, Woff3, b_off, (void*)offb, 256);
  // logits = Q_hi @ w_attn (plain bf16), out bf16
  gemm_mfma<4, (1 << 20), true><<<dim3(1, M_TOT / 128), blk, 0, stream>>>(
      Q3, 512, Wat, b_attn, (void*)logitb, 128);
  msda_sample_v3<<<dim3(M_TOT / 8), blk, 0, stream>>>(
      offb, logitb, valb, ref_pts, sshapes, lstart, samp3);
  // out = samp (hi|lo|hi-wrap) @ w_out x3, out f32
  gemm_mfma<12, 512, false><<<dim3(2, M_TOT / 128), blk, 0, stream>>>(
      samp3, 512, Wo3, b_out, (void*)out, 256);
}